// Round 2
// baseline (538.550 us; speedup 1.0000x reference)
//
#include <hip/hip_runtime.h>
#include <hip/hip_bf16.h>
#include <math.h>

#define BB 32
#define SS 4096
#define DMEM 512
#define DATT 512

typedef short short8 __attribute__((ext_vector_type(8)));
typedef float floatx4 __attribute__((ext_vector_type(4)));

__device__ inline short f2bf(float x) {
    unsigned u = __float_as_uint(x);
    unsigned r = (u + 0x7fffu + ((u >> 16) & 1u)) >> 16;
    return (short)(r & 0xffffu);
}

__device__ inline float fast_tanh(float x) {
    float e = __expf(2.0f * x);
    return 1.0f - 2.0f / (e + 1.0f);
}

// async 16B global->LDS DMA; lds base wave-uniform, HW adds lane*16.
__device__ inline void gld_lds16(const void* g, void* l) {
    __builtin_amdgcn_global_load_lds(
        (const __attribute__((address_space(1))) unsigned int*)g,
        (__attribute__((address_space(3))) unsigned int*)l, 16, 0, 0);
}

// ---------------- prep kernels ----------------

__global__ void prep_wt_kernel(const float* __restrict__ Wm, short* __restrict__ Wt) {
    const int n0 = blockIdx.x * 32;
    const int k0 = blockIdx.y * 32;
    const int t = threadIdx.x;
    const int r = t >> 5, c = t & 31;
    __shared__ float lds[32 * 33];
#pragma unroll
    for (int j = 0; j < 4; ++j) {
        int kk = r + j * 8;
        lds[kk * 33 + c] = Wm[(size_t)(k0 + kk) * 512 + n0 + c];
    }
    __syncthreads();
#pragma unroll
    for (int j = 0; j < 4; ++j) {
        int nn = r + j * 8;
        Wt[(size_t)(n0 + nn) * 512 + k0 + c] = f2bf(lds[c * 33 + nn]);
    }
}

// h = hidden @ Wh, k-split x4, atomic combine (h pre-zeroed)
__global__ void prep_h_kernel(const float* __restrict__ hidden, const float* __restrict__ Wh,
                              float* __restrict__ h) {
    const int b = blockIdx.x;
    const int n = blockIdx.y * 256 + threadIdx.x;
    const int kc = blockIdx.z;
    float acc = 0.f;
#pragma unroll 8
    for (int k = kc * 128; k < kc * 128 + 128; ++k)
        acc += hidden[b * 512 + k] * Wh[(size_t)k * 512 + n];
    atomicAdd(&h[b * 512 + n], acc);
}

// ---------------- score: reg-staged bf16 A, prefetch-overlapped, __syncthreads sync ----
// 1-D grid 4096 = 32b*32st*4nt, decoded so the 4 nt-siblings (same A tile) sit 8
// blocks apart => same XCD slot under round-robin dispatch => A echo-reads hit L2.
// 256 thr = 4 waves (2m x 2n), wave tile 64x64 (4x4 frags).
// A: fp32 global -> float4 regs (coalesced; 16 lanes cover one row's 256B slice)
//    -> single v_cvt_pk_bf16 -> ds_write_b64 into tileA with ROW PITCH 144B.
//    144B = 36 banks: consecutive rows shift 4 banks, so staging writes and
//    frag ds_read_b128 are bank-even with NO swizzle (m136: 2-way = free).
//    Halves A's LDS traffic vs fp32 staging and converts each element ONCE.
// B: global_load_lds DMA, double-buffered; global-side XOR chunk swizzle keeps
//    LDS linear (DMA constraint); frag reads land 2 lanes/bank.
// Pipeline (conservative, full-drain __syncthreads only — no raw barriers):
//   per kt: issue A(kt+1)->regs + B(kt+1) DMA->other buf BEFORE compute(kt);
//   compute covers the load latency; sync; write A(kt+1) from regs; sync.
// vs baseline (issue DMA, immediately drain, compute) this hides the full
// staging latency behind 32 MFMAs each K-step.

__global__ __launch_bounds__(256, 3)
void score_kernel(const float* __restrict__ memory,
                  const float* __restrict__ coverage,
                  const short* __restrict__ Wt,
                  const float* __restrict__ h,
                  const float* __restrict__ Wc,
                  const float* __restrict__ v,
                  float* __restrict__ scoreParts) {
    const int g = blockIdx.x;
    const int inner = g & 7;
    const int nt = (g >> 3) & 3;
    const int stb = (g >> 5) * 8 + inner;  // 0..1023
    const int st = stb & 31;
    const int b = stb >> 5;
    const int n0 = nt * 128;
    const int s0 = st * 128;

    const int tid = threadIdx.x;
    const int lane = tid & 63;
    const int wave = tid >> 6;
    const int wm = wave & 1;
    const int wn = wave >> 1;
    const int col = lane & 15;
    const int q = lane >> 4;

    __shared__ __align__(16) short tileA[128 * 72];      // bf16, pitch 144B, 18 KB
    __shared__ __align__(16) short tileB[2][128 * 64];   // bf16 dbuf, 2x16 KB
    __shared__ float covS[128];
    __shared__ float sred[2][128];

    if (tid < 128) covS[tid] = coverage[(size_t)b * SS + s0 + tid];

    const float4* gA4 = (const float4*)(memory + ((size_t)b * SS + s0) * 512);  // row = 128 float4
    const char* gB = (const char*)(Wt + (size_t)n0 * 512);                      // row pitch 1024B

    const int ar0 = tid >> 4;   // A: 16 lanes cover one row's 256B fp32 slice
    const int ac16 = tid & 15;
    const int br0 = tid >> 3;   // B: 8 chunks of 16B per row
    const int bc0 = tid & 7;

    float4 apf[8];

    floatx4 acc[4][4];
#pragma unroll
    for (int mi = 0; mi < 4; ++mi)
#pragma unroll
        for (int ni = 0; ni < 4; ++ni)
            acc[mi][ni] = (floatx4){0.f, 0.f, 0.f, 0.f};

    // ---- prologue: stage tile 0 ----
#pragma unroll
    for (int i = 0; i < 8; ++i) {
        int row = i * 16 + ar0;
        apf[i] = gA4[(size_t)row * 128 + ac16];          // kt=0 slice
    }
    {
        char* ldsB = (char*)(&tileB[0][0]) + wave * 1024;
#pragma unroll
        for (int it = 0; it < 4; ++it) {
            int row = it * 32 + br0;
            int gch = bc0 ^ (row & 7);
            gld_lds16(gB + (size_t)row * 1024 + gch * 16, ldsB + it * 4096);
        }
    }
#pragma unroll
    for (int i = 0; i < 8; ++i) {
        int row = i * 16 + ar0;
        union { __hip_bfloat162 h2; unsigned u; } p0, p1;
        p0.h2 = __float22bfloat162_rn(make_float2(apf[i].x, apf[i].y));
        p1.h2 = __float22bfloat162_rn(make_float2(apf[i].z, apf[i].w));
        uint2 w; w.x = p0.u; w.y = p1.u;
        *(uint2*)((char*)tileA + row * 144 + ac16 * 8) = w;
    }
    __syncthreads();   // drains B DMA + A writes; tile 0 ready

    for (int kt = 0; kt < 8; ++kt) {
        // ---- issue next-tile loads BEFORE compute: A into regs, B DMA into other buf ----
        if (kt < 7) {
#pragma unroll
            for (int i = 0; i < 8; ++i) {
                int row = i * 16 + ar0;
                apf[i] = gA4[(size_t)row * 128 + (kt + 1) * 16 + ac16];
            }
            char* ldsB = (char*)(&tileB[(kt + 1) & 1][0]) + wave * 1024;
#pragma unroll
            for (int it = 0; it < 4; ++it) {
                int row = it * 32 + br0;
                int gch = bc0 ^ (row & 7);
                gld_lds16(gB + (size_t)row * 1024 + (kt + 1) * 128 + gch * 16,
                          ldsB + it * 4096);
            }
        }

        // ---- compute tile kt (covers the prefetch latency) ----
        const char* bbase = (const char*)(&tileB[kt & 1][0]);
#pragma unroll
        for (int ks = 0; ks < 2; ++ks) {
            short8 af[4], bf[4];
            const int ca = ks * 64 + q * 16;   // byte offset in A row (k = 32ks+8q)
            const int cb = ks * 4 + q;         // B 16B chunk index
#pragma unroll
            for (int mi = 0; mi < 4; ++mi) {
                int row = wm * 64 + mi * 16 + col;
                af[mi] = *(const short8*)((const char*)tileA + row * 144 + ca);
            }
#pragma unroll
            for (int ni = 0; ni < 4; ++ni) {
                int row = wn * 64 + ni * 16 + col;
                bf[ni] = *(const short8*)(bbase + row * 128 + ((cb ^ (row & 7)) * 16));
            }
#pragma unroll
            for (int mi = 0; mi < 4; ++mi)
#pragma unroll
                for (int ni = 0; ni < 4; ++ni)
                    acc[mi][ni] = __builtin_amdgcn_mfma_f32_16x16x32_bf16(af[mi], bf[ni], acc[mi][ni], 0, 0, 0);
        }

        __syncthreads();   // tileA reads done everywhere; B DMA drained (was covered by compute)

        if (kt < 7) {
            // convert + write A(kt+1) from regs (data already on-chip)
#pragma unroll
            for (int i = 0; i < 8; ++i) {
                int row = i * 16 + ar0;
                union { __hip_bfloat162 h2; unsigned u; } p0, p1;
                p0.h2 = __float22bfloat162_rn(make_float2(apf[i].x, apf[i].y));
                p1.h2 = __float22bfloat162_rn(make_float2(apf[i].z, apf[i].w));
                uint2 w; w.x = p0.u; w.y = p1.u;
                *(uint2*)((char*)tileA + row * 144 + ac16 * 8) = w;
            }
            __syncthreads();   // tile kt+1 (A) visible
        }
    }

    // epilogue: score += tanh(m + h + cov*Wc) * v, reduce over n
    float hv[4], wcv[4], vv[4];
#pragma unroll
    for (int ni = 0; ni < 4; ++ni) {
        int n = n0 + wn * 64 + ni * 16 + col;
        hv[ni] = h[b * 512 + n];
        wcv[ni] = Wc[n];
        vv[ni] = v[n];
    }
    float rowAcc[4][4];
#pragma unroll
    for (int mi = 0; mi < 4; ++mi)
#pragma unroll
        for (int r = 0; r < 4; ++r)
            rowAcc[mi][r] = 0.f;
#pragma unroll
    for (int mi = 0; mi < 4; ++mi) {
#pragma unroll
        for (int r = 0; r < 4; ++r) {
            float cv = covS[wm * 64 + mi * 16 + q * 4 + r];
#pragma unroll
            for (int ni = 0; ni < 4; ++ni) {
                float val = acc[mi][ni][r] + hv[ni] + cv * wcv[ni];
                rowAcc[mi][r] += fast_tanh(val) * vv[ni];
            }
        }
    }
#pragma unroll
    for (int off = 1; off < 16; off <<= 1)
#pragma unroll
        for (int mi = 0; mi < 4; ++mi)
#pragma unroll
            for (int r = 0; r < 4; ++r)
                rowAcc[mi][r] += __shfl_xor(rowAcc[mi][r], off, 64);

    if (col == 0) {
#pragma unroll
        for (int mi = 0; mi < 4; ++mi)
#pragma unroll
            for (int r = 0; r < 4; ++r)
                sred[wn][wm * 64 + mi * 16 + q * 4 + r] = rowAcc[mi][r];
    }
    __syncthreads();
    if (tid < 128)
        scoreParts[(size_t)nt * BB * SS + (size_t)b * SS + s0 + tid] =
            sred[0][tid] + sred[1][tid];
}

// ---------------- softmax (sums 4 score parts) ----------------
__global__ void softmax_kernel(const float* __restrict__ scoreParts,
                               const unsigned char* __restrict__ pad,
                               float* __restrict__ attn_out) {
    const int b = blockIdx.x;
    const int tid = threadIdx.x;  // 1024
    const int wave = tid >> 6, lane = tid & 63;
    __shared__ float redMax[16];
    __shared__ float redSum[16];

    float vals[4];
    float mx = -INFINITY;
#pragma unroll
    for (int i = 0; i < 4; ++i) {
        size_t idx = (size_t)b * SS + tid + i * 1024;
        float s = scoreParts[idx] + scoreParts[(size_t)BB * SS + idx]
                + scoreParts[2 * (size_t)BB * SS + idx] + scoreParts[3 * (size_t)BB * SS + idx];
        if (pad[idx]) s = -INFINITY;
        vals[i] = s;
        mx = fmaxf(mx, s);
    }
#pragma unroll
    for (int off = 32; off >= 1; off >>= 1) mx = fmaxf(mx, __shfl_xor(mx, off, 64));
    if (lane == 0) redMax[wave] = mx;
    __syncthreads();
    float gmax = -INFINITY;
#pragma unroll
    for (int w = 0; w < 16; ++w) gmax = fmaxf(gmax, redMax[w]);

    float sum = 0.f;
#pragma unroll
    for (int i = 0; i < 4; ++i) {
        float e = __expf(vals[i] - gmax);
        vals[i] = e;
        sum += e;
    }
#pragma unroll
    for (int off = 32; off >= 1; off >>= 1) sum += __shfl_xor(sum, off, 64);
    if (lane == 0) redSum[wave] = sum;
    __syncthreads();
    float gsum = 0.f;
#pragma unroll
    for (int w = 0; w < 16; ++w) gsum += redSum[w];
    const float inv = 1.0f / gsum;
#pragma unroll
    for (int i = 0; i < 4; ++i)
        attn_out[(size_t)b * SS + tid + i * 1024] = vals[i] * inv;
}

// ---------------- context ----------------
__global__ __launch_bounds__(256)
void context_kernel(const float* __restrict__ memory,
                    const float* __restrict__ attn,
                    float* __restrict__ ctx) {
    const int sc = blockIdx.x;
    const int dh = blockIdx.y;
    const int b  = blockIdx.z;
    const int t = threadIdx.x;
    const int c = t & 63;
    const int r = t >> 6;

    __shared__ float wS[128];
    __shared__ float4 red[3][64];

    if (t < 128) wS[t] = attn[(size_t)b * SS + sc * 128 + t];
    __syncthreads();

    const float4* m4 = (const float4*)(memory + ((size_t)b * SS + sc * 128) * DMEM) + dh * 64 + c;
    float4 acc = {0.f, 0.f, 0.f, 0.f};
#pragma unroll 8
    for (int i = 0; i < 32; ++i) {
        int row = i * 4 + r;
        float w = wS[row];
        float4 f = m4[(size_t)row * 128];
        acc.x += w * f.x; acc.y += w * f.y; acc.z += w * f.z; acc.w += w * f.w;
    }
    if (r > 0) red[r - 1][c] = acc;
    __syncthreads();
    if (r == 0) {
#pragma unroll
        for (int j = 0; j < 3; ++j) {
            float4 o = red[j][c];
            acc.x += o.x; acc.y += o.y; acc.z += o.z; acc.w += o.w;
        }
        float* dst = &ctx[b * 512 + dh * 256 + c * 4];
        atomicAdd(dst + 0, acc.x);
        atomicAdd(dst + 1, acc.y);
        atomicAdd(dst + 2, acc.z);
        atomicAdd(dst + 3, acc.w);
    }
}

// ---------------- launch ----------------
extern "C" void kernel_launch(void* const* d_in, const int* in_sizes, int n_in,
                              void* d_out, int out_size, void* d_ws, size_t ws_size,
                              hipStream_t stream) {
    (void)in_sizes; (void)n_in; (void)out_size; (void)ws_size;
    const float* hidden   = (const float*)d_in[0];
    const float* memory   = (const float*)d_in[1];
    const unsigned char* mem_pad = (const unsigned char*)d_in[2];
    const float* coverage = (const float*)d_in[3];
    const float* Wh       = (const float*)d_in[4];
    const float* Wm       = (const float*)d_in[5];
    const float* Wc       = (const float*)d_in[6];
    const float* v        = (const float*)d_in[7];

    char* ws = (char*)d_ws;
    short* Wt    = (short*)ws;                      // 512 KB
    float* h     = (float*)(ws + 512 * 1024);       // 64 KB
    float* parts = (float*)(ws + 576 * 1024);       // 4 * 512 KB

    float* ctx  = (float*)d_out;
    float* attn = (float*)d_out + BB * 512;

    hipMemsetAsync(ctx, 0, BB * 512 * sizeof(float), stream);
    hipMemsetAsync(h, 0, BB * 512 * sizeof(float), stream);
    prep_wt_kernel<<<dim3(16, 16), dim3(256), 0, stream>>>(Wm, Wt);
    prep_h_kernel<<<dim3(32, 2, 4), dim3(256), 0, stream>>>(hidden, Wh, h);
    score_kernel<<<dim3(4096), dim3(256), 0, stream>>>(memory, coverage, Wt, h, Wc, v, parts);
    softmax_kernel<<<dim3(BB), dim3(1024), 0, stream>>>(parts, mem_pad, attn);
    context_kernel<<<dim3(32, 2, BB), dim3(256), 0, stream>>>(memory, attn, ctx);
}

// Round 3
// 499.902 us; speedup vs baseline: 1.0773x; 1.0773x over previous
//
#include <hip/hip_runtime.h>
#include <hip/hip_bf16.h>
#include <math.h>

#define BB 32
#define SS 4096
#define DMEM 512
#define DATT 512

typedef short short8 __attribute__((ext_vector_type(8)));
typedef float floatx4 __attribute__((ext_vector_type(4)));

__device__ inline short f2bf(float x) {
    unsigned u = __float_as_uint(x);
    unsigned r = (u + 0x7fffu + ((u >> 16) & 1u)) >> 16;
    return (short)(r & 0xffffu);
}

__device__ inline float fast_tanh(float x) {
    float e = __expf(2.0f * x);
    return 1.0f - 2.0f / (e + 1.0f);
}

// async 16B global->LDS DMA; lds base wave-uniform, HW adds lane*16.
__device__ inline void gld_lds16(const void* g, void* l) {
    __builtin_amdgcn_global_load_lds(
        (const __attribute__((address_space(1))) unsigned int*)g,
        (__attribute__((address_space(3))) unsigned int*)l, 16, 0, 0);
}

// ---------------- prep kernels ----------------

__global__ void prep_wt_kernel(const float* __restrict__ Wm, short* __restrict__ Wt) {
    const int n0 = blockIdx.x * 32;
    const int k0 = blockIdx.y * 32;
    const int t = threadIdx.x;
    const int r = t >> 5, c = t & 31;
    __shared__ float lds[32 * 33];
#pragma unroll
    for (int j = 0; j < 4; ++j) {
        int kk = r + j * 8;
        lds[kk * 33 + c] = Wm[(size_t)(k0 + kk) * 512 + n0 + c];
    }
    __syncthreads();
#pragma unroll
    for (int j = 0; j < 4; ++j) {
        int nn = r + j * 8;
        Wt[(size_t)(n0 + nn) * 512 + k0 + c] = f2bf(lds[c * 33 + nn]);
    }
}

// h = hidden @ Wh, k-split x4, atomic combine (h pre-zeroed)
__global__ void prep_h_kernel(const float* __restrict__ hidden, const float* __restrict__ Wh,
                              float* __restrict__ h) {
    const int b = blockIdx.x;
    const int n = blockIdx.y * 256 + threadIdx.x;
    const int kc = blockIdx.z;
    float acc = 0.f;
#pragma unroll 8
    for (int k = kc * 128; k < kc * 128 + 128; ++k)
        acc += hidden[b * 512 + k] * Wh[(size_t)k * 512 + n];
    atomicAdd(&h[b * 512 + n], acc);
}

// ---------------- score: reg-staged bf16 A (XOR-swizzled tile), prefetch pipeline ----
// 1-D grid 4096 = 32b*32st*4nt, decoded so the 4 nt-siblings (same A tile) sit 8
// blocks apart => same XCD slot under round-robin dispatch => A echo-reads hit L2.
// 256 thr = 4 waves (2m x 2n), wave tile 64x64 (4x4 frags).
// A: fp32 global -> float4 regs (coalesced; 16 lanes cover one row's 256B slice)
//    -> single v_cvt_pk_bf16 -> 8B LDS write into tileA.
//    tileA layout == tileB layout: 128 rows x 128B, 16B chunk index XORed with
//    (row&7).  Frag ds_read_b128 lands 2 lanes/bank (free, m136); the 8B staging
//    writes cover all 32 banks once per 16-lane row-group (conflict-free).
//    [R2 post-mortem: 144B pitch was 8-way conflicted -> 2^22 extra cycles; this
//    swizzle is the measured-zero-conflict layout B already uses.]
// B: global_load_lds DMA, double-buffered; global-side XOR chunk swizzle keeps
//    LDS linear (DMA constraint); frag reads land 2 lanes/bank.
// Pipeline (conservative, full-drain __syncthreads only):
//   per kt: issue A(kt+1)->regs + B(kt+1) DMA->other buf BEFORE compute(kt);
//   compute covers the load latency; sync; write A(kt+1) from regs; sync.

__global__ __launch_bounds__(256, 3)
void score_kernel(const float* __restrict__ memory,
                  const float* __restrict__ coverage,
                  const short* __restrict__ Wt,
                  const float* __restrict__ h,
                  const float* __restrict__ Wc,
                  const float* __restrict__ v,
                  float* __restrict__ scoreParts) {
    const int g = blockIdx.x;
    const int inner = g & 7;
    const int nt = (g >> 3) & 3;
    const int stb = (g >> 5) * 8 + inner;  // 0..1023
    const int st = stb & 31;
    const int b = stb >> 5;
    const int n0 = nt * 128;
    const int s0 = st * 128;

    const int tid = threadIdx.x;
    const int lane = tid & 63;
    const int wave = tid >> 6;
    const int wm = wave & 1;
    const int wn = wave >> 1;
    const int col = lane & 15;
    const int q = lane >> 4;

    __shared__ __align__(16) short tileA[128 * 64];      // bf16, swizzled, 16 KB
    __shared__ __align__(16) short tileB[2][128 * 64];   // bf16 dbuf, 2x16 KB
    __shared__ float covS[128];
    __shared__ float sred[2][128];

    if (tid < 128) covS[tid] = coverage[(size_t)b * SS + s0 + tid];

    const float4* gA4 = (const float4*)(memory + ((size_t)b * SS + s0) * 512);  // row = 128 float4
    const char* gB = (const char*)(Wt + (size_t)n0 * 512);                      // row pitch 1024B

    const int ar0 = tid >> 4;   // A: 16 lanes cover one row's 256B fp32 slice
    const int ac16 = tid & 15;
    const int br0 = tid >> 3;   // B: 8 chunks of 16B per row
    const int bc0 = tid & 7;

    float4 apf[8];

    floatx4 acc[4][4];
#pragma unroll
    for (int mi = 0; mi < 4; ++mi)
#pragma unroll
        for (int ni = 0; ni < 4; ++ni)
            acc[mi][ni] = (floatx4){0.f, 0.f, 0.f, 0.f};

    // A staging write address (swizzled): row bf16 slice [ac16*8, ac16*8+8)
    //   chunk = ac16>>1, half = ac16&1  ->  (chunk^(row&7))*16 + half*8
    // ---- prologue: stage tile 0 ----
#pragma unroll
    for (int i = 0; i < 8; ++i) {
        int row = i * 16 + ar0;
        apf[i] = gA4[(size_t)row * 128 + ac16];          // kt=0 slice
    }
    {
        char* ldsB = (char*)(&tileB[0][0]) + wave * 1024;
#pragma unroll
        for (int it = 0; it < 4; ++it) {
            int row = it * 32 + br0;
            int gch = bc0 ^ (row & 7);
            gld_lds16(gB + (size_t)row * 1024 + gch * 16, ldsB + it * 4096);
        }
    }
#pragma unroll
    for (int i = 0; i < 8; ++i) {
        int row = i * 16 + ar0;
        union { __hip_bfloat162 h2; unsigned u; } p0, p1;
        p0.h2 = __float22bfloat162_rn(make_float2(apf[i].x, apf[i].y));
        p1.h2 = __float22bfloat162_rn(make_float2(apf[i].z, apf[i].w));
        uint2 w; w.x = p0.u; w.y = p1.u;
        int swzoff = (((ac16 >> 1) ^ (row & 7)) << 4) + ((ac16 & 1) << 3);
        *(uint2*)((char*)tileA + row * 128 + swzoff) = w;
    }
    __syncthreads();   // drains B DMA + A writes; tile 0 ready

    for (int kt = 0; kt < 8; ++kt) {
        // ---- issue next-tile loads BEFORE compute: A into regs, B DMA into other buf ----
        if (kt < 7) {
#pragma unroll
            for (int i = 0; i < 8; ++i) {
                int row = i * 16 + ar0;
                apf[i] = gA4[(size_t)row * 128 + (kt + 1) * 16 + ac16];
            }
            char* ldsB = (char*)(&tileB[(kt + 1) & 1][0]) + wave * 1024;
#pragma unroll
            for (int it = 0; it < 4; ++it) {
                int row = it * 32 + br0;
                int gch = bc0 ^ (row & 7);
                gld_lds16(gB + (size_t)row * 1024 + (kt + 1) * 128 + gch * 16,
                          ldsB + it * 4096);
            }
        }

        // ---- compute tile kt (covers the prefetch latency) ----
        const char* bbase = (const char*)(&tileB[kt & 1][0]);
#pragma unroll
        for (int ks = 0; ks < 2; ++ks) {
            short8 af[4], bf[4];
            const int cb = ks * 4 + q;         // logical 16B chunk (A and B identical)
#pragma unroll
            for (int mi = 0; mi < 4; ++mi) {
                int row = wm * 64 + mi * 16 + col;
                af[mi] = *(const short8*)((const char*)tileA + row * 128 + ((cb ^ (row & 7)) * 16));
            }
#pragma unroll
            for (int ni = 0; ni < 4; ++ni) {
                int row = wn * 64 + ni * 16 + col;
                bf[ni] = *(const short8*)(bbase + row * 128 + ((cb ^ (row & 7)) * 16));
            }
#pragma unroll
            for (int mi = 0; mi < 4; ++mi)
#pragma unroll
                for (int ni = 0; ni < 4; ++ni)
                    acc[mi][ni] = __builtin_amdgcn_mfma_f32_16x16x32_bf16(af[mi], bf[ni], acc[mi][ni], 0, 0, 0);
        }

        __syncthreads();   // tileA reads done everywhere; B DMA drained (was covered by compute)

        if (kt < 7) {
            // convert + write A(kt+1) from regs (data already on-chip)
#pragma unroll
            for (int i = 0; i < 8; ++i) {
                int row = i * 16 + ar0;
                union { __hip_bfloat162 h2; unsigned u; } p0, p1;
                p0.h2 = __float22bfloat162_rn(make_float2(apf[i].x, apf[i].y));
                p1.h2 = __float22bfloat162_rn(make_float2(apf[i].z, apf[i].w));
                uint2 w; w.x = p0.u; w.y = p1.u;
                int swzoff = (((ac16 >> 1) ^ (row & 7)) << 4) + ((ac16 & 1) << 3);
                *(uint2*)((char*)tileA + row * 128 + swzoff) = w;
            }
            __syncthreads();   // tile kt+1 (A) visible
        }
    }

    // epilogue: score += tanh(m + h + cov*Wc) * v, reduce over n
    float hv[4], wcv[4], vv[4];
#pragma unroll
    for (int ni = 0; ni < 4; ++ni) {
        int n = n0 + wn * 64 + ni * 16 + col;
        hv[ni] = h[b * 512 + n];
        wcv[ni] = Wc[n];
        vv[ni] = v[n];
    }
    float rowAcc[4][4];
#pragma unroll
    for (int mi = 0; mi < 4; ++mi)
#pragma unroll
        for (int r = 0; r < 4; ++r)
            rowAcc[mi][r] = 0.f;
#pragma unroll
    for (int mi = 0; mi < 4; ++mi) {
#pragma unroll
        for (int r = 0; r < 4; ++r) {
            float cv = covS[wm * 64 + mi * 16 + q * 4 + r];
#pragma unroll
            for (int ni = 0; ni < 4; ++ni) {
                float val = acc[mi][ni][r] + hv[ni] + cv * wcv[ni];
                rowAcc[mi][r] += fast_tanh(val) * vv[ni];
            }
        }
    }
#pragma unroll
    for (int off = 1; off < 16; off <<= 1)
#pragma unroll
        for (int mi = 0; mi < 4; ++mi)
#pragma unroll
            for (int r = 0; r < 4; ++r)
                rowAcc[mi][r] += __shfl_xor(rowAcc[mi][r], off, 64);

    if (col == 0) {
#pragma unroll
        for (int mi = 0; mi < 4; ++mi)
#pragma unroll
            for (int r = 0; r < 4; ++r)
                sred[wn][wm * 64 + mi * 16 + q * 4 + r] = rowAcc[mi][r];
    }
    __syncthreads();
    if (tid < 128)
        scoreParts[(size_t)nt * BB * SS + (size_t)b * SS + s0 + tid] =
            sred[0][tid] + sred[1][tid];
}

// ---------------- softmax (sums 4 score parts) ----------------
__global__ void softmax_kernel(const float* __restrict__ scoreParts,
                               const unsigned char* __restrict__ pad,
                               float* __restrict__ attn_out) {
    const int b = blockIdx.x;
    const int tid = threadIdx.x;  // 1024
    const int wave = tid >> 6, lane = tid & 63;
    __shared__ float redMax[16];
    __shared__ float redSum[16];

    float vals[4];
    float mx = -INFINITY;
#pragma unroll
    for (int i = 0; i < 4; ++i) {
        size_t idx = (size_t)b * SS + tid + i * 1024;
        float s = scoreParts[idx] + scoreParts[(size_t)BB * SS + idx]
                + scoreParts[2 * (size_t)BB * SS + idx] + scoreParts[3 * (size_t)BB * SS + idx];
        if (pad[idx]) s = -INFINITY;
        vals[i] = s;
        mx = fmaxf(mx, s);
    }
#pragma unroll
    for (int off = 32; off >= 1; off >>= 1) mx = fmaxf(mx, __shfl_xor(mx, off, 64));
    if (lane == 0) redMax[wave] = mx;
    __syncthreads();
    float gmax = -INFINITY;
#pragma unroll
    for (int w = 0; w < 16; ++w) gmax = fmaxf(gmax, redMax[w]);

    float sum = 0.f;
#pragma unroll
    for (int i = 0; i < 4; ++i) {
        float e = __expf(vals[i] - gmax);
        vals[i] = e;
        sum += e;
    }
#pragma unroll
    for (int off = 32; off >= 1; off >>= 1) sum += __shfl_xor(sum, off, 64);
    if (lane == 0) redSum[wave] = sum;
    __syncthreads();
    float gsum = 0.f;
#pragma unroll
    for (int w = 0; w < 16; ++w) gsum += redSum[w];
    const float inv = 1.0f / gsum;
#pragma unroll
    for (int i = 0; i < 4; ++i)
        attn_out[(size_t)b * SS + tid + i * 1024] = vals[i] * inv;
}

// ---------------- context ----------------
__global__ __launch_bounds__(256)
void context_kernel(const float* __restrict__ memory,
                    const float* __restrict__ attn,
                    float* __restrict__ ctx) {
    const int sc = blockIdx.x;
    const int dh = blockIdx.y;
    const int b  = blockIdx.z;
    const int t = threadIdx.x;
    const int c = t & 63;
    const int r = t >> 6;

    __shared__ float wS[128];
    __shared__ float4 red[3][64];

    if (t < 128) wS[t] = attn[(size_t)b * SS + sc * 128 + t];
    __syncthreads();

    const float4* m4 = (const float4*)(memory + ((size_t)b * SS + sc * 128) * DMEM) + dh * 64 + c;
    float4 acc = {0.f, 0.f, 0.f, 0.f};
#pragma unroll 8
    for (int i = 0; i < 32; ++i) {
        int row = i * 4 + r;
        float w = wS[row];
        float4 f = m4[(size_t)row * 128];
        acc.x += w * f.x; acc.y += w * f.y; acc.z += w * f.z; acc.w += w * f.w;
    }
    if (r > 0) red[r - 1][c] = acc;
    __syncthreads();
    if (r == 0) {
#pragma unroll
        for (int j = 0; j < 3; ++j) {
            float4 o = red[j][c];
            acc.x += o.x; acc.y += o.y; acc.z += o.z; acc.w += o.w;
        }
        float* dst = &ctx[b * 512 + dh * 256 + c * 4];
        atomicAdd(dst + 0, acc.x);
        atomicAdd(dst + 1, acc.y);
        atomicAdd(dst + 2, acc.z);
        atomicAdd(dst + 3, acc.w);
    }
}

// ---------------- launch ----------------
extern "C" void kernel_launch(void* const* d_in, const int* in_sizes, int n_in,
                              void* d_out, int out_size, void* d_ws, size_t ws_size,
                              hipStream_t stream) {
    (void)in_sizes; (void)n_in; (void)out_size; (void)ws_size;
    const float* hidden   = (const float*)d_in[0];
    const float* memory   = (const float*)d_in[1];
    const unsigned char* mem_pad = (const unsigned char*)d_in[2];
    const float* coverage = (const float*)d_in[3];
    const float* Wh       = (const float*)d_in[4];
    const float* Wm       = (const float*)d_in[5];
    const float* Wc       = (const float*)d_in[6];
    const float* v        = (const float*)d_in[7];

    char* ws = (char*)d_ws;
    short* Wt    = (short*)ws;                      // 512 KB
    float* h     = (float*)(ws + 512 * 1024);       // 64 KB
    float* parts = (float*)(ws + 576 * 1024);       // 4 * 512 KB

    float* ctx  = (float*)d_out;
    float* attn = (float*)d_out + BB * 512;

    hipMemsetAsync(ctx, 0, BB * 512 * sizeof(float), stream);
    hipMemsetAsync(h, 0, BB * 512 * sizeof(float), stream);
    prep_wt_kernel<<<dim3(16, 16), dim3(256), 0, stream>>>(Wm, Wt);
    prep_h_kernel<<<dim3(32, 2, 4), dim3(256), 0, stream>>>(hidden, Wh, h);
    score_kernel<<<dim3(4096), dim3(256), 0, stream>>>(memory, coverage, Wt, h, Wc, v, parts);
    softmax_kernel<<<dim3(BB), dim3(1024), 0, stream>>>(parts, mem_pad, attn);
    context_kernel<<<dim3(32, 2, BB), dim3(256), 0, stream>>>(memory, attn, ctx);
}

// Round 5
// 471.980 us; speedup vs baseline: 1.1410x; 1.0592x over previous
//
#include <hip/hip_runtime.h>
#include <hip/hip_bf16.h>
#include <math.h>

#define BB 32
#define SS 4096
#define DMEM 512
#define DATT 512

typedef short short8 __attribute__((ext_vector_type(8)));
typedef float floatx4 __attribute__((ext_vector_type(4)));

__device__ inline short f2bf(float x) {
    unsigned u = __float_as_uint(x);
    unsigned r = (u + 0x7fffu + ((u >> 16) & 1u)) >> 16;
    return (short)(r & 0xffffu);
}

__device__ inline float fast_tanh(float x) {
    float e = __expf(2.0f * x);
    return 1.0f - 2.0f / (e + 1.0f);
}

// async 16B global->LDS DMA; lds base wave-uniform, HW adds lane*16.
__device__ inline void gld_lds16(const void* g, void* l) {
    __builtin_amdgcn_global_load_lds(
        (const __attribute__((address_space(1))) unsigned int*)g,
        (__attribute__((address_space(3))) unsigned int*)l, 16, 0, 0);
}

// ---------------- prep kernels (unchanged, proven) ----------------

__global__ void prep_wt_kernel(const float* __restrict__ Wm, short* __restrict__ Wt) {
    const int n0 = blockIdx.x * 32;
    const int k0 = blockIdx.y * 32;
    const int t = threadIdx.x;
    const int r = t >> 5, c = t & 31;
    __shared__ float lds[32 * 33];
#pragma unroll
    for (int j = 0; j < 4; ++j) {
        int kk = r + j * 8;
        lds[kk * 33 + c] = Wm[(size_t)(k0 + kk) * 512 + n0 + c];
    }
    __syncthreads();
#pragma unroll
    for (int j = 0; j < 4; ++j) {
        int nn = r + j * 8;
        Wt[(size_t)(n0 + nn) * 512 + k0 + c] = f2bf(lds[c * 33 + nn]);
    }
}

__global__ void prep_h_kernel(const float* __restrict__ hidden, const float* __restrict__ Wh,
                              float* __restrict__ h) {
    const int b = blockIdx.x;
    const int n = blockIdx.y * 256 + threadIdx.x;
    const int kc = blockIdx.z;
    float acc = 0.f;
#pragma unroll 8
    for (int k = kc * 128; k < kc * 128 + 128; ++k)
        acc += hidden[b * 512 + k] * Wh[(size_t)k * 512 + n];
    atomicAdd(&h[b * 512 + n], acc);
}

// ---------------- fused score + partial softmax + context (split-S flash) ----------
// Block (b, st): s-rows [st*128, +128), ALL n=512, ALL k=512.  1024 blocks, 512 thr
// = 8 waves (2m x 4n), wave tile 64x128 -> acc[4][8] frags.
// A (memory rows): fp32 global -> regs -> bf16 -> LDS, R3's zero-conflict XOR layout.
// B (Wt): 512x64 k-slices via global_load_lds, double-buffered, global-side XOR.
// After GEMM: tanh/v reduce -> 128 tile scores -> tile-softmax (m, p=exp(s-m), l)
// -> PV from ORIGINAL fp32 memory (tile is L3-resident: no extra HBM) -> ctxPart.
// Unnormalized p goes STRAIGHT INTO the attn output buffer (saves a workspace
// buffer; R4 post-mortem: total ws use must stay <= 2.625 MB proven envelope).
// combine_kernel merges tiles: gmax/gsum, rescales attn in place, writes ctx.
// LDS: B dbuf 128K + A 16K + 4K misc = 148K -> 1 block/CU, 8 waves. MFMA phase
// (~2500 CU-cycles/kt) covers prefetch latency despite single-block residency.

#define FK_MISC (147456)

__global__ __launch_bounds__(512, 2)
void fused_kernel(const float* __restrict__ memory,
                  const float* __restrict__ coverage,
                  const unsigned char* __restrict__ pad,
                  const short* __restrict__ Wt,
                  const float* __restrict__ h,
                  const float* __restrict__ Wc,
                  const float* __restrict__ v,
                  float* __restrict__ pOut,     // = attn output buffer (unnormalized p)
                  float* __restrict__ mWS,
                  float* __restrict__ lWS,
                  float* __restrict__ ctxPart) {
    const int blk = blockIdx.x;
    const int b = blk >> 5;
    const int st = blk & 31;
    const int s0 = st * 128;

    const int tid = threadIdx.x;
    const int lane = tid & 63;
    const int wave = tid >> 6;     // 0..7
    const int wm = wave & 1;       // 2-way m split
    const int wn = wave >> 1;      // 4-way n split
    const int col = lane & 15;
    const int q = lane >> 4;

    __shared__ __align__(16) char smem[FK_MISC + 4096];
    short* tileB0 = (short*)smem;                       // 64 KB
    short* tileB1 = (short*)(smem + 65536);             // 64 KB
    short* tileA  = (short*)(smem + 131072);            // 16 KB, swizzled 128B rows
    float* covS   = (float*)(smem + FK_MISC);           // 512 B
    float* sred   = (float*)(smem + FK_MISC + 512);     // [4][128] = 2 KB
    float* scoreS = (float*)(smem + FK_MISC + 2560);    // 512 B
    float* pS     = (float*)(smem + FK_MISC + 3072);    // 512 B
    float* mlS    = (float*)(smem + FK_MISC + 3584);    // m, l
    float4* red4  = (float4*)smem;                      // PV reduce, aliases tileB

    if (tid < 128) covS[tid] = coverage[(size_t)b * SS + s0 + tid];

    const float4* gA4 = (const float4*)(memory + ((size_t)b * SS + s0) * 512);  // row=128 f4
    const char* gB = (const char*)Wt;                   // row pitch 1024B, 512 rows

    const int ar0 = tid >> 4;      // 0..31: 16 lanes cover one A row's 256B slice
    const int ac16 = tid & 15;

    float4 apf[4];

    floatx4 acc[4][8];
#pragma unroll
    for (int mi = 0; mi < 4; ++mi)
#pragma unroll
        for (int ni = 0; ni < 8; ++ni)
            acc[mi][ni] = (floatx4){0.f, 0.f, 0.f, 0.f};

    // ---- prologue: stage tile 0 ----
#pragma unroll
    for (int p = 0; p < 4; ++p)
        apf[p] = gA4[(size_t)(p * 32 + ar0) * 128 + ac16];
#pragma unroll
    for (int it = 0; it < 8; ++it) {
        int ci = (it * 8 + wave) * 64 + lane;
        int row = ci >> 3;
        int gch = (ci & 7) ^ (row & 7);
        gld_lds16(gB + (size_t)row * 1024 + gch * 16,
                  (char*)tileB0 + (it * 8 + wave) * 1024);
    }
#pragma unroll
    for (int p = 0; p < 4; ++p) {
        int row = p * 32 + ar0;
        union { __hip_bfloat162 h2; unsigned u; } p0, p1;
        p0.h2 = __float22bfloat162_rn(make_float2(apf[p].x, apf[p].y));
        p1.h2 = __float22bfloat162_rn(make_float2(apf[p].z, apf[p].w));
        uint2 w; w.x = p0.u; w.y = p1.u;
        int swzoff = (((ac16 >> 1) ^ (row & 7)) << 4) + ((ac16 & 1) << 3);
        *(uint2*)((char*)tileA + row * 128 + swzoff) = w;
    }
    __syncthreads();

    for (int kt = 0; kt < 8; ++kt) {
        if (kt < 7) {
#pragma unroll
            for (int p = 0; p < 4; ++p)
                apf[p] = gA4[(size_t)(p * 32 + ar0) * 128 + (kt + 1) * 16 + ac16];
            char* ldsB = (char*)(((kt + 1) & 1) ? tileB1 : tileB0);
#pragma unroll
            for (int it = 0; it < 8; ++it) {
                int ci = (it * 8 + wave) * 64 + lane;
                int row = ci >> 3;
                int gch = (ci & 7) ^ (row & 7);
                gld_lds16(gB + (size_t)row * 1024 + (kt + 1) * 128 + gch * 16,
                          ldsB + (it * 8 + wave) * 1024);
            }
        }

        const char* bbase = (const char*)((kt & 1) ? tileB1 : tileB0);
#pragma unroll
        for (int ks = 0; ks < 2; ++ks) {
            short8 af[4], bf[8];
            const int cb = ks * 4 + q;
#pragma unroll
            for (int mi = 0; mi < 4; ++mi) {
                int row = wm * 64 + mi * 16 + col;
                af[mi] = *(const short8*)((const char*)tileA + row * 128 + ((cb ^ (row & 7)) * 16));
            }
#pragma unroll
            for (int ni = 0; ni < 8; ++ni) {
                int row = wn * 128 + ni * 16 + col;
                bf[ni] = *(const short8*)(bbase + row * 128 + ((cb ^ (row & 7)) * 16));
            }
#pragma unroll
            for (int mi = 0; mi < 4; ++mi)
#pragma unroll
                for (int ni = 0; ni < 8; ++ni)
                    acc[mi][ni] = __builtin_amdgcn_mfma_f32_16x16x32_bf16(af[mi], bf[ni], acc[mi][ni], 0, 0, 0);
        }

        __syncthreads();

        if (kt < 7) {
#pragma unroll
            for (int p = 0; p < 4; ++p) {
                int row = p * 32 + ar0;
                union { __hip_bfloat162 h2; unsigned u; } p0, p1;
                p0.h2 = __float22bfloat162_rn(make_float2(apf[p].x, apf[p].y));
                p1.h2 = __float22bfloat162_rn(make_float2(apf[p].z, apf[p].w));
                uint2 w; w.x = p0.u; w.y = p1.u;
                int swzoff = (((ac16 >> 1) ^ (row & 7)) << 4) + ((ac16 & 1) << 3);
                *(uint2*)((char*)tileA + row * 128 + swzoff) = w;
            }
            __syncthreads();
        }
    }

    // ---- epilogue: tile scores = sum_n tanh(acc + h + cov*Wc) * v ----
    float hv[8], wcv[8], vv[8];
#pragma unroll
    for (int ni = 0; ni < 8; ++ni) {
        int n = wn * 128 + ni * 16 + col;
        hv[ni] = h[b * 512 + n];
        wcv[ni] = Wc[n];
        vv[ni] = v[n];
    }
    float rowAcc[4][4];
#pragma unroll
    for (int mi = 0; mi < 4; ++mi)
#pragma unroll
        for (int r = 0; r < 4; ++r)
            rowAcc[mi][r] = 0.f;
#pragma unroll
    for (int mi = 0; mi < 4; ++mi) {
#pragma unroll
        for (int r = 0; r < 4; ++r) {
            float cv = covS[wm * 64 + mi * 16 + q * 4 + r];
#pragma unroll
            for (int ni = 0; ni < 8; ++ni) {
                float val = acc[mi][ni][r] + hv[ni] + cv * wcv[ni];
                rowAcc[mi][r] += fast_tanh(val) * vv[ni];
            }
        }
    }
#pragma unroll
    for (int off = 1; off < 16; off <<= 1)
#pragma unroll
        for (int mi = 0; mi < 4; ++mi)
#pragma unroll
            for (int r = 0; r < 4; ++r)
                rowAcc[mi][r] += __shfl_xor(rowAcc[mi][r], off, 64);

    if (col == 0) {
#pragma unroll
        for (int mi = 0; mi < 4; ++mi)
#pragma unroll
            for (int r = 0; r < 4; ++r)
                sred[wn * 128 + wm * 64 + mi * 16 + q * 4 + r] = rowAcc[mi][r];
    }
    __syncthreads();

    // ---- tile softmax (m, p, l) ----
    if (tid < 128) {
        float sc = sred[tid] + sred[128 + tid] + sred[256 + tid] + sred[384 + tid];
        if (pad[(size_t)b * SS + s0 + tid]) sc = -INFINITY;
        scoreS[tid] = sc;
    }
    __syncthreads();
    if (tid < 64) {
        float mx = fmaxf(scoreS[tid], scoreS[tid + 64]);
#pragma unroll
        for (int off = 32; off >= 1; off >>= 1) mx = fmaxf(mx, __shfl_xor(mx, off, 64));
        if (tid == 0) mlS[0] = mx;
    }
    __syncthreads();
    const float mtile = mlS[0];
    if (tid < 128) pS[tid] = __expf(scoreS[tid] - mtile);
    __syncthreads();
    if (tid < 64) {
        float sm = pS[tid] + pS[tid + 64];
#pragma unroll
        for (int off = 32; off >= 1; off >>= 1) sm += __shfl_xor(sm, off, 64);
        if (tid == 0) mlS[1] = sm;
    }
    __syncthreads();

    if (tid < 128) pOut[(size_t)b * SS + s0 + tid] = pS[tid];
    if (tid == 0) {
        mWS[b * 32 + st] = mtile;
        lWS[b * 32 + st] = mlS[1];
    }

    // ---- PV: ctxPart[d] = sum_s p[s] * memory_fp32[s,d]  (tile is L3-hot) ----
    const int sg = tid >> 7;       // 4 groups of 32 s-rows
    const int dc = tid & 127;      // float4 column
    const float4* m4 = (const float4*)(memory + ((size_t)b * SS + s0) * 512);
    float4 a4 = {0.f, 0.f, 0.f, 0.f};
#pragma unroll 8
    for (int i = 0; i < 32; ++i) {
        int s = sg * 32 + i;
        float w = pS[s];
        float4 f = m4[(size_t)s * 128 + dc];
        a4.x += w * f.x; a4.y += w * f.y; a4.z += w * f.z; a4.w += w * f.w;
    }
    red4[sg * 128 + dc] = a4;      // aliases tileB (GEMM reads all complete)
    __syncthreads();
    if (tid < 128) {
        float4 r0 = red4[tid], r1 = red4[128 + tid], r2 = red4[256 + tid], r3 = red4[384 + tid];
        float4 o;
        o.x = r0.x + r1.x + r2.x + r3.x;
        o.y = r0.y + r1.y + r2.y + r3.y;
        o.z = r0.z + r1.z + r2.z + r3.z;
        o.w = r0.w + r1.w + r2.w + r3.w;
        ((float4*)(ctxPart + ((size_t)(b * 32 + st)) * 512))[tid] = o;
    }
}

// ---------------- combine: cross-tile softmax merge -> attn (in place), ctx --------
__global__ __launch_bounds__(512)
void combine_kernel(const float* __restrict__ mWS,
                    const float* __restrict__ lWS,
                    const float* __restrict__ ctxPart,
                    float* __restrict__ ctx,
                    float* __restrict__ attn) {
    const int b = blockIdx.x;
    const int tid = threadIdx.x;   // 512
    __shared__ float scaleS[32];
    __shared__ float gS[2];

    if (tid < 64) {
        float mv = (tid < 32) ? mWS[b * 32 + tid] : -INFINITY;
#pragma unroll
        for (int off = 32; off >= 1; off >>= 1) mv = fmaxf(mv, __shfl_xor(mv, off, 64));
        if (tid == 0) gS[0] = mv;
    }
    __syncthreads();
    const float gmax = gS[0];
    if (tid < 64) {
        float sc = 0.f, lv = 0.f;
        if (tid < 32) {
            sc = __expf(mWS[b * 32 + tid] - gmax);
            scaleS[tid] = sc;
            lv = lWS[b * 32 + tid] * sc;
        }
#pragma unroll
        for (int off = 32; off >= 1; off >>= 1) lv += __shfl_xor(lv, off, 64);
        if (tid == 0) gS[1] = lv;
    }
    __syncthreads();
    const float inv = 1.0f / gS[1];

    // ctx[b, d] = sum_st ctxPart[st, d] * scale[st] * inv   (no atomics)
    float facc = 0.f;
#pragma unroll 8
    for (int st = 0; st < 32; ++st)
        facc += ctxPart[((size_t)(b * 32 + st)) * 512 + tid] * scaleS[st];
    ctx[b * 512 + tid] = facc * inv;

    // attn[b, s] holds unnormalized p -> rescale in place
#pragma unroll
    for (int j = 0; j < 8; ++j) {
        size_t idx = (size_t)b * SS + j * 512 + tid;
        attn[idx] = attn[idx] * scaleS[(j * 512 + tid) >> 7] * inv;
    }
}

// ---------------- launch ----------------
extern "C" void kernel_launch(void* const* d_in, const int* in_sizes, int n_in,
                              void* d_out, int out_size, void* d_ws, size_t ws_size,
                              hipStream_t stream) {
    (void)in_sizes; (void)n_in; (void)out_size; (void)ws_size;
    const float* hidden   = (const float*)d_in[0];
    const float* memory   = (const float*)d_in[1];
    const unsigned char* mem_pad = (const unsigned char*)d_in[2];
    const float* coverage = (const float*)d_in[3];
    const float* Wh       = (const float*)d_in[4];
    const float* Wm       = (const float*)d_in[5];
    const float* Wc       = (const float*)d_in[6];
    const float* v        = (const float*)d_in[7];

    char* ws = (char*)d_ws;
    short* Wt      = (short*)ws;                       // 512 KB
    float* h       = (float*)(ws + 512 * 1024);        // 64 KB
    float* mWS     = (float*)(ws + 576 * 1024);        // 4 KB (32 x 32)
    float* lWS     = (float*)(ws + 580 * 1024);        // 4 KB
    float* ctxPart = (float*)(ws + 584 * 1024);        // 2 MB (32 x 32 x 512)
    // total ws use: 584 KB + 2 MB = 2.57 MB  (<= 2.625 MB proven envelope)

    float* ctx  = (float*)d_out;
    float* attn = (float*)d_out + BB * 512;            // doubles as p buffer

    hipMemsetAsync(h, 0, BB * 512 * sizeof(float), stream);
    prep_wt_kernel<<<dim3(16, 16), dim3(256), 0, stream>>>(Wm, Wt);
    prep_h_kernel<<<dim3(32, 2, 4), dim3(256), 0, stream>>>(hidden, Wh, h);
    fused_kernel<<<dim3(BB * 32), dim3(512), 0, stream>>>(
        memory, coverage, mem_pad, Wt, h, Wc, v, attn, mWS, lWS, ctxPart);
    combine_kernel<<<dim3(BB), dim3(512), 0, stream>>>(mWS, lWS, ctxPart, ctx, attn);
}